// Round 15
// baseline (657.061 us; speedup 1.0000x reference)
//
#include <hip/hip_runtime.h>
#include <hip/hip_bf16.h>
#include <cstddef>

#define SP 3136          // 56*56
#define CIN 64
#define COUT 256
#define NB 32
#define NEG_SLOPE 0.01f

typedef __attribute__((ext_vector_type(8))) short short8v;  // 8 bf16 (4 VGPRs)
typedef __attribute__((ext_vector_type(4))) float f32x4;    // MFMA accumulator

__device__ __forceinline__ float bfr(ushort h) {
    union { uint u; float f; } c; c.u = ((uint)h) << 16; return c.f;
}
__device__ __forceinline__ void split_bf(float v, ushort& hi, ushort& lo) {
    __hip_bfloat16 h = __float2bfloat16(v);
    float r = v - __bfloat162float(h);
    __hip_bfloat16 l2 = __float2bfloat16(r);
    hi = *(ushort*)&h; lo = *(ushort*)&l2;
}

// XOR swizzle: logical 8-ushort group g of row -> physical ushort offset
#define SWZ(row, g) ((((g) ^ ((row) & 7))) * 8)

// ---------------------------------------------------------------------------
// pack_w: W[co][ci][ky][kx] f32 -> fragment-contiguous planes
// Wf[tap][ks][cig][co][ce]: lane l of a wave reads 16B at
// ((tap*2+ks)*4 + (l>>4))*256 + co(l); lanes 0..15 -> 256B contiguous.
// ---------------------------------------------------------------------------
__global__ __launch_bounds__(256)
void pack_w(const float* __restrict__ W, ushort* __restrict__ wh, ushort* __restrict__ wl)
{
    const int id = blockIdx.x * 256 + threadIdx.x;   // 147456 = 9*256*64
    const int ci = id & 63, co = (id >> 6) & 255, tap = id >> 14;
    float v = W[(size_t)(co * 64 + ci) * 9 + tap];
    ushort hi, lo; split_bf(v, hi, lo);
    const int ks = ci >> 5, cig = (ci >> 3) & 3, ce = ci & 7;
    const size_t o = (((size_t)(tap * 2 + ks) * 4 + cig) * 256 + co) * 8 + ce;
    wh[o] = hi; wl[o] = lo;
}

// ---------------------------------------------------------------------------
// conv_fused v2: 3x3 circular conv, bf16x3 MFMA, barrier-free tap loop.
// (unchanged from round 14 — measured off top-5)
// ---------------------------------------------------------------------------
__global__ __launch_bounds__(256, 2)
void conv_fused(const float* __restrict__ xsrc, const float* __restrict__ nsrc,
                const ushort* __restrict__ Wf_hi, const ushort* __restrict__ Wf_lo,
                const float* __restrict__ bias,
                ushort* __restrict__ h1h, ushort* __restrict__ h1l,
                ushort* __restrict__ hnh, ushort* __restrict__ hnl)
{
    __shared__ __align__(16) ushort Bh[4 * 58 * 64]; // 29 KB
    __shared__ __align__(16) ushort Bl[4 * 58 * 64]; // 29 KB
    const int tid = threadIdx.x;
    const int w = tid >> 6, l = tid & 63;
    const int ch  = blockIdx.x;                      // co half: 0..1
    const int rp  = blockIdx.y;                      // 0..27
    const int img = blockIdx.z;                      // 0..63
    const int imgb = img & (NB - 1);
    const int y0 = rp * 2, p0 = rp * 112;
    const int co_w = ch * 128 + w * 32;              // wave's co base

    const float* __restrict__ src = (img < NB ? xsrc : nsrc) + (size_t)imgb * CIN * SP;
    ushort* __restrict__ dh = (img < NB ? h1h : hnh) + (size_t)imgb * COUT * SP;
    ushort* __restrict__ dl = (img < NB ? h1l : hnl) + (size_t)imgb * COUT * SP;

    int sy[4];
    #pragma unroll
    for (int j = 0; j < 4; ++j) sy[j] = (y0 + 55 + j) % 56;   // padded row y0+j

    // ---- stage B once: raw f32 -> split bf16 -> LDS [j][x][ci] swizzled ----
    {
        const int ci = tid >> 2, seg = tid & 3;      // 64 ci x 4 col-segments(14)
        #pragma unroll
        for (int j = 0; j < 4; ++j) {
            const float* r = src + (size_t)ci * SP + sy[j] * 56 + seg * 14;
            #pragma unroll
            for (int c = 0; c < 14; ++c) {
                float v = r[c];
                ushort hi, lo; split_bf(v, hi, lo);
                const int x = seg * 14 + c + 1;      // padded col = orig col + 1
                const int idx = ((j * 58 + x) << 6) + (((ci >> 3) ^ (x & 7)) << 3) + (ci & 7);
                Bh[idx] = hi; Bl[idx] = lo;
            }
        }
        // wrap columns: x=0 <- orig col 55, x=57 <- orig col 0 (512 slots, 2/thr)
        #pragma unroll
        for (int s = 0; s < 2; ++s) {
            const int slot = tid * 2 + s;
            const int j2 = slot >> 7, ci2 = (slot >> 1) & 63, side = slot & 1;
            const float* r2 = src + (size_t)ci2 * SP + sy[j2] * 56;
            const float v = side ? r2[0] : r2[55];
            const int x = side ? 57 : 0;
            ushort hi, lo; split_bf(v, hi, lo);
            const int idx = ((j2 * 58 + x) << 6) + (((ci2 >> 3) ^ (x & 7)) << 3) + (ci2 & 7);
            Bh[idx] = hi; Bl[idx] = lo;
        }
    }
    __syncthreads();                                 // the ONLY barrier

    f32x4 acc[2][7];
    {
        const int rr = (l >> 4) * 4;
        #pragma unroll
        for (int m = 0; m < 2; ++m) {
            const int cb = co_w + 16 * m + rr;
            f32x4 bv = { bias[cb], bias[cb + 1], bias[cb + 2], bias[cb + 3] };
            #pragma unroll
            for (int nf = 0; nf < 7; ++nf) acc[m][nf] = bv;
        }
    }

    // per-nf spatial decomposition (lane-dependent, tap-invariant)
    int b58[7], bx[7];
    #pragma unroll
    for (int nf = 0; nf < 7; ++nf) {
        const int sp = nf * 16 + (l & 15);           // 0..111
        const int ry = (sp >= 56) ? 1 : 0;
        const int xx = sp - ry * 56;
        b58[nf] = ry * 58 + xx;
        bx[nf]  = xx;
    }

    for (int tap = 0; tap < 9; ++tap) {
        const int dy = tap / 3, dx = tap - dy * 3;
        const int toff = dy * 58 + dx;
        #pragma unroll
        for (int ks = 0; ks < 2; ++ks) {
            const int grp = ks * 4 + (l >> 4);
            short8v ah[2], alv[2];
            #pragma unroll
            for (int m = 0; m < 2; ++m) {            // A: direct global gather (L2)
                const int co_l = co_w + 16 * m + (l & 15);
                const size_t off = ((((size_t)(tap * 2 + ks) * 4 + (l >> 4)) * 256 + co_l)) * 8;
                ah[m]  = *(const short8v*)(Wf_hi + off);
                alv[m] = *(const short8v*)(Wf_lo + off);
            }
            #pragma unroll
            for (int nf = 0; nf < 7; ++nf) {
                const int x  = bx[nf] + dx;
                const int bi = ((b58[nf] + toff) << 6) + ((grp ^ (x & 7)) << 3);
                short8v bh  = *(const short8v*)&Bh[bi];
                short8v blv = *(const short8v*)&Bl[bi];
                #pragma unroll
                for (int m = 0; m < 2; ++m) {
                    acc[m][nf] = __builtin_amdgcn_mfma_f32_16x16x32_bf16(ah[m],  bh,  acc[m][nf], 0, 0, 0);
                    acc[m][nf] = __builtin_amdgcn_mfma_f32_16x16x32_bf16(ah[m],  blv, acc[m][nf], 0, 0, 0);
                    acc[m][nf] = __builtin_amdgcn_mfma_f32_16x16x32_bf16(alv[m], bh,  acc[m][nf], 0, 0, 0);
                }
            }
        }
    }

    // epilogue: D row=(l>>4)*4+r -> co, col=l&15 -> sp (verified m89 layout)
    const int rr = (l >> 4) * 4, cc = l & 15;
    #pragma unroll
    for (int m = 0; m < 2; ++m) {
        const int cb = co_w + 16 * m + rr;
        #pragma unroll
        for (int nf = 0; nf < 7; ++nf) {
            const int p = p0 + nf * 16 + cc;
            #pragma unroll
            for (int r = 0; r < 4; ++r) {
                ushort hi, lo; split_bf(acc[m][nf][r], hi, lo);
                dh[(size_t)(cb + r) * SP + p] = hi;
                dl[(size_t)(cb + r) * SP + p] = lo;
            }
        }
    }
}

// ---------------------------------------------------------------------------
// gemm_a_mfma v3: a[b][n][m] = LeakyReLU( sum_k h1[n,k]*hn[m,k] ), bf16x3.
// 256 thr = 4 waves (2n x 2m), wave 32n x 32m, tile 64n x 64m.
// Grid 32 img x 16 tiles = 512 blocks = 2 blocks/CU (fixes r10's 1/CU limit).
// Register prefetch (pa[4]+pb[4]) + SWZ LDS (0-conflict pattern from r14).
// 256-thread template = the RA-proven envelope (conv 88 / agg 68 VGPR, no spill).
// ---------------------------------------------------------------------------
__global__ __launch_bounds__(256, 2)
void gemm_a_mfma(const ushort* __restrict__ h1h, const ushort* __restrict__ h1l,
                 const ushort* __restrict__ hnh, const ushort* __restrict__ hnl,
                 float* __restrict__ attn)
{
    __shared__ __align__(16) ushort Ah[64][64];
    __shared__ __align__(16) ushort Al[64][64];
    __shared__ __align__(16) ushort Bh[64][64];
    __shared__ __align__(16) ushort Bl[64][64];
    const int tid = threadIdx.x;
    const int w = tid >> 6, l = tid & 63;
    const int wn = w >> 1, wm = w & 1;              // wave grid 2n x 2m
    const int img = blockIdx.x, tile = blockIdx.y;
    const int n0 = (tile & 3) * 64, m0 = (tile >> 2) * 64;

    const ushort* __restrict__ Ahg = h1h + ((size_t)img * COUT + n0) * SP;
    const ushort* __restrict__ Alg = h1l + ((size_t)img * COUT + n0) * SP;
    const ushort* __restrict__ Bhg = hnh + ((size_t)img * COUT + m0) * SP;
    const ushort* __restrict__ Blg = hnl + ((size_t)img * COUT + m0) * SP;

    f32x4 acc[2][2];
    #pragma unroll
    for (int i = 0; i < 2; ++i)
        #pragma unroll
        for (int j = 0; j < 2; ++j) acc[i][j] = (f32x4){0.f, 0.f, 0.f, 0.f};

    // staging: 64 rows x 8 groups x 2 planes = 1024 uint4 per matrix;
    // 256 thr -> 4 groups/thread for A and 4 for B.
    const int ap = tid >> 7, arow = (tid & 127) >> 1, ag0 = (tid & 1) * 4;
    const ushort* __restrict__ Asrc = ap ? Alg : Ahg;
    ushort (* __restrict__ Adst)[64] = ap ? Al : Ah;
    const ushort* __restrict__ Bsrc = ap ? Blg : Bhg;
    ushort (* __restrict__ Bdst)[64] = ap ? Bl : Bh;

    const ushort* aptr = Asrc + (size_t)arow * SP + ag0 * 8;
    const ushort* bptr = Bsrc + (size_t)arow * SP + ag0 * 8;

    uint4 pa[4], pb[4];
    #pragma unroll
    for (int j = 0; j < 4; ++j) { pa[j] = ((const uint4*)aptr)[j]; pb[j] = ((const uint4*)bptr)[j]; }

    for (int k0 = 0; k0 < SP; k0 += 64) {
        #pragma unroll
        for (int j = 0; j < 4; ++j) {
            *(uint4*)&Adst[arow][SWZ(arow, ag0 + j)] = pa[j];
            *(uint4*)&Bdst[arow][SWZ(arow, ag0 + j)] = pb[j];
        }
        __syncthreads();

        {   // prefetch next K-tile (clamped: last iter re-reads current)
            const int kn = (k0 + 64 < SP) ? k0 + 64 : k0;
            #pragma unroll
            for (int j = 0; j < 4; ++j) {
                pa[j] = ((const uint4*)(aptr + kn))[j];
                pb[j] = ((const uint4*)(bptr + kn))[j];
            }
        }

        #pragma unroll
        for (int ks = 0; ks < 2; ++ks) {
            const int grp = ks * 4 + (l >> 4);
            short8v ahf[2], alf[2], bhf[2], blf[2];
            #pragma unroll
            for (int i = 0; i < 2; ++i) {
                const int ar_ = 32 * wn + 16 * i + (l & 15);
                ahf[i] = *(const short8v*)&Ah[ar_][SWZ(ar_, grp)];
                alf[i] = *(const short8v*)&Al[ar_][SWZ(ar_, grp)];
                const int br_ = 32 * wm + 16 * i + (l & 15);
                bhf[i] = *(const short8v*)&Bh[br_][SWZ(br_, grp)];
                blf[i] = *(const short8v*)&Bl[br_][SWZ(br_, grp)];
            }
            #pragma unroll
            for (int i = 0; i < 2; ++i)
                #pragma unroll
                for (int j = 0; j < 2; ++j) {
                    acc[i][j] = __builtin_amdgcn_mfma_f32_16x16x32_bf16(ahf[i], bhf[j], acc[i][j], 0, 0, 0);
                    acc[i][j] = __builtin_amdgcn_mfma_f32_16x16x32_bf16(ahf[i], blf[j], acc[i][j], 0, 0, 0);
                    acc[i][j] = __builtin_amdgcn_mfma_f32_16x16x32_bf16(alf[i], bhf[j], acc[i][j], 0, 0, 0);
                }
        }
        __syncthreads();
    }

    const int rr = (l >> 4) * 4, cc = l & 15;
    float* __restrict__ aimg = attn + (size_t)img * COUT * COUT;
    #pragma unroll
    for (int i = 0; i < 2; ++i) {
        const int nb = n0 + 32 * wn + 16 * i + rr;
        #pragma unroll
        for (int j = 0; j < 2; ++j) {
            const int m = m0 + 32 * wm + 16 * j + cc;
            #pragma unroll
            for (int r = 0; r < 4; ++r) {
                float v = acc[i][j][r];
                v = (v >= 0.f) ? v : NEG_SLOPE * v;
                aimg[(size_t)(nb + r) * COUT + m] = v;
            }
        }
    }
}

// ---------------------------------------------------------------------------
// softmax over axis n (dim=1) per (b,m) column, in place. (unchanged)
// ---------------------------------------------------------------------------
__global__ __launch_bounds__(64)
void softmax_k(float* __restrict__ attn)
{
    const int b = blockIdx.y;
    const int m = blockIdx.x * 64 + threadIdx.x;
    float* a = attn + (size_t)b * COUT * COUT;
    float mx = -1e30f;
    for (int n_ = 0; n_ < COUT; ++n_) mx = fmaxf(mx, a[n_ * COUT + m]);
    float s = 0.f;
    for (int n_ = 0; n_ < COUT; ++n_) s += expf(a[n_ * COUT + m] - mx);
    float inv = 1.f / s;
    for (int n_ = 0; n_ < COUT; ++n_)
        a[n_ * COUT + m] = expf(a[n_ * COUT + m] - mx) * inv;
}

// ---------------------------------------------------------------------------
// gemm_agg_mfma: out[n][f] = 0.1 * sum_m attn[n][m]*h1[m][f] + 0.9 * h1[n][f]
// (unchanged from round 9/10)
// ---------------------------------------------------------------------------
__global__ __launch_bounds__(256, 2)
void gemm_agg_mfma(const float* __restrict__ attn,
                   const ushort* __restrict__ h1h, const ushort* __restrict__ h1l,
                   float* __restrict__ out)
{
    __shared__ __align__(16) ushort Ah[128][72];
    __shared__ __align__(16) ushort Al[128][72];
    __shared__ __align__(16) ushort Bh[112][72];
    __shared__ __align__(16) ushort Bl[112][72];
    const int tid = threadIdx.x, w = tid >> 6, l = tid & 63;
    const int f0 = blockIdx.x * 112;
    const int n0 = blockIdx.y * 128;
    const int img = blockIdx.z;

    const float*  __restrict__ A  = attn + (size_t)img * COUT * COUT;
    const ushort* __restrict__ Hh = h1h + (size_t)img * COUT * SP;
    const ushort* __restrict__ Hl = h1l + (size_t)img * COUT * SP;

    f32x4 acc[2][7];
    #pragma unroll
    for (int nf = 0; nf < 2; ++nf)
        #pragma unroll
        for (int mf = 0; mf < 7; ++mf) acc[nf][mf] = (f32x4){0.f, 0.f, 0.f, 0.f};

    const int ar = tid >> 1, ac = (tid & 1) * 32;
    const int bp = tid >> 7, bm = (tid & 127) >> 1, bf = (tid & 1) * 56;
    const ushort* __restrict__ Bsrc = bp ? Hl : Hh;
    ushort (* __restrict__ Bdst)[72] = bp ? Bl : Bh;

    for (int k0 = 0; k0 < COUT; k0 += 64) {
        {
            const float* g = A + (size_t)(n0 + ar) * COUT + k0 + ac;
            uint* dh = (uint*)&Ah[ar][ac];
            uint* dl = (uint*)&Al[ar][ac];
            #pragma unroll
            for (int q = 0; q < 8; ++q) {
                float4 v = *(const float4*)(g + 4 * q);
                ushort h0, l0, h1_, l1_, h2, l2, h3, l3;
                split_bf(v.x, h0, l0); split_bf(v.y, h1_, l1_);
                split_bf(v.z, h2, l2); split_bf(v.w, h3, l3);
                dh[2 * q]     = (uint)h0 | ((uint)h1_ << 16);
                dh[2 * q + 1] = (uint)h2 | ((uint)h3  << 16);
                dl[2 * q]     = (uint)l0 | ((uint)l1_ << 16);
                dl[2 * q + 1] = (uint)l2 | ((uint)l3  << 16);
            }
        }
        {
            const ushort* g = Bsrc + (size_t)(k0 + bm) * SP + f0 + bf;
            #pragma unroll
            for (int q = 0; q < 7; ++q) {
                uint4 v = *(const uint4*)(g + 8 * q);
                const ushort* vp = (const ushort*)&v;
                #pragma unroll
                for (int e = 0; e < 8; ++e)
                    Bdst[bf + 8 * q + e][bm] = vp[e];
            }
        }
        __syncthreads();
        #pragma unroll
        for (int ks = 0; ks < 2; ++ks) {
            const int kb = ks * 32 + (l >> 4) * 8;
            short8v ah[2], alv[2];
            #pragma unroll
            for (int nf = 0; nf < 2; ++nf) {
                const int row = 32 * w + 16 * nf + (l & 15);
                ah[nf]  = *(const short8v*)&Ah[row][kb];
                alv[nf] = *(const short8v*)&Al[row][kb];
            }
            #pragma unroll
            for (int mf = 0; mf < 7; ++mf) {
                const int br = mf * 16 + (l & 15);
                short8v bh  = *(const short8v*)&Bh[br][kb];
                short8v blv = *(const short8v*)&Bl[br][kb];
                #pragma unroll
                for (int nf = 0; nf < 2; ++nf) {
                    acc[nf][mf] = __builtin_amdgcn_mfma_f32_16x16x32_bf16(ah[nf],  bh,  acc[nf][mf], 0, 0, 0);
                    acc[nf][mf] = __builtin_amdgcn_mfma_f32_16x16x32_bf16(ah[nf],  blv, acc[nf][mf], 0, 0, 0);
                    acc[nf][mf] = __builtin_amdgcn_mfma_f32_16x16x32_bf16(alv[nf], bh,  acc[nf][mf], 0, 0, 0);
                }
            }
        }
        __syncthreads();
    }

    const int rr = (l >> 4) * 4, cc = l & 15;
    float* __restrict__ orow = out + (size_t)img * COUT * SP;
    #pragma unroll
    for (int nf = 0; nf < 2; ++nf) {
        const int nb = n0 + 32 * w + 16 * nf + rr;
        #pragma unroll
        for (int mf = 0; mf < 7; ++mf) {
            const int f = f0 + 16 * mf + cc;
            #pragma unroll
            for (int r = 0; r < 4; ++r) {
                const int n = nb + r;
                float h = bfr(Hh[(size_t)n * SP + f]) + bfr(Hl[(size_t)n * SP + f]);
                orow[(size_t)n * SP + f] = 0.1f * acc[nf][mf][r] + 0.9f * h;
            }
        }
    }
}

// ---------------------------------------------------------------------------
extern "C" void kernel_launch(void* const* d_in, const int* in_sizes, int n_in,
                              void* d_out, int out_size, void* d_ws, size_t ws_size,
                              hipStream_t stream)
{
    const float* x    = (const float*)d_in[0];
    const float* nn   = (const float*)d_in[1];
    const float* W    = (const float*)d_in[2];
    const float* bias = (const float*)d_in[3];
    float* out = (float*)d_out;

    // ws (111.2 MB): h1b_hi (51.4) | h1b_lo (51.4) | zone (8.39):
    //   conv phase: Wf hi/lo (1.2 MB); gemm phase: attn f32 (overlaps dead Wf).
    ushort* h1b_hi = (ushort*)d_ws;
    ushort* h1b_lo = h1b_hi + (size_t)NB * COUT * SP;
    char*   zone   = (char*)(h1b_lo + (size_t)NB * COUT * SP);
    ushort* Wf_hi  = (ushort*)zone;
    ushort* Wf_lo  = Wf_hi + 9 * 256 * 64;
    float*  attn   = (float*)zone;          // overwrites Wf after convs complete
    // d_out (102.8 MB): hnb_hi | hnb_lo until gemm_agg_mfma overwrites with out f32.
    ushort* hnb_hi = (ushort*)d_out;
    ushort* hnb_lo = hnb_hi + (size_t)NB * COUT * SP;

    pack_w    <<<576, 256, 0, stream>>>(W, Wf_hi, Wf_lo);
    conv_fused<<<dim3(2, 28, 2 * NB), 256, 0, stream>>>(x, nn, Wf_hi, Wf_lo, bias,
                                                        h1b_hi, h1b_lo, hnb_hi, hnb_lo);
    gemm_a_mfma  <<<dim3(32, 16),    256, 0, stream>>>(h1b_hi, h1b_lo, hnb_hi, hnb_lo, attn);
    softmax_k    <<<dim3(4, NB),     64,  0, stream>>>(attn);
    gemm_agg_mfma<<<dim3(28, 2, NB), 256, 0, stream>>>(attn, h1b_hi, h1b_lo, out);
}

// Round 16
// 408.657 us; speedup vs baseline: 1.6079x; 1.6079x over previous
//
#include <hip/hip_runtime.h>
#include <hip/hip_bf16.h>
#include <cstddef>

#define SP 3136          // 56*56
#define CIN 64
#define COUT 256
#define NB 32
#define NEG_SLOPE 0.01f

typedef __attribute__((ext_vector_type(8))) short short8v;  // 8 bf16 (4 VGPRs)
typedef __attribute__((ext_vector_type(4))) float f32x4;    // MFMA accumulator

__device__ __forceinline__ float bfr(ushort h) {
    union { uint u; float f; } c; c.u = ((uint)h) << 16; return c.f;
}
__device__ __forceinline__ void split_bf(float v, ushort& hi, ushort& lo) {
    __hip_bfloat16 h = __float2bfloat16(v);
    float r = v - __bfloat162float(h);
    __hip_bfloat16 l2 = __float2bfloat16(r);
    hi = *(ushort*)&h; lo = *(ushort*)&l2;
}

// XOR swizzle: logical 8-ushort group g of row -> physical ushort offset
#define SWZ(row, g) ((((g) ^ ((row) & 7))) * 8)

// ---------------------------------------------------------------------------
// pack_w: W[co][ci][ky][kx] f32 -> fragment-contiguous planes (unchanged)
// ---------------------------------------------------------------------------
__global__ __launch_bounds__(256)
void pack_w(const float* __restrict__ W, ushort* __restrict__ wh, ushort* __restrict__ wl)
{
    const int id = blockIdx.x * 256 + threadIdx.x;   // 147456 = 9*256*64
    const int ci = id & 63, co = (id >> 6) & 255, tap = id >> 14;
    float v = W[(size_t)(co * 64 + ci) * 9 + tap];
    ushort hi, lo; split_bf(v, hi, lo);
    const int ks = ci >> 5, cig = (ci >> 3) & 3, ce = ci & 7;
    const size_t o = (((size_t)(tap * 2 + ks) * 4 + cig) * 256 + co) * 8 + ce;
    wh[o] = hi; wl[o] = lo;
}

// ---------------------------------------------------------------------------
// conv_fused v2: 3x3 circular conv, bf16x3 MFMA, barrier-free tap loop.
// (unchanged from round 14 — measured off top-5)
// ---------------------------------------------------------------------------
__global__ __launch_bounds__(256, 2)
void conv_fused(const float* __restrict__ xsrc, const float* __restrict__ nsrc,
                const ushort* __restrict__ Wf_hi, const ushort* __restrict__ Wf_lo,
                const float* __restrict__ bias,
                ushort* __restrict__ h1h, ushort* __restrict__ h1l,
                ushort* __restrict__ hnh, ushort* __restrict__ hnl)
{
    __shared__ __align__(16) ushort Bh[4 * 58 * 64]; // 29 KB
    __shared__ __align__(16) ushort Bl[4 * 58 * 64]; // 29 KB
    const int tid = threadIdx.x;
    const int w = tid >> 6, l = tid & 63;
    const int ch  = blockIdx.x;                      // co half: 0..1
    const int rp  = blockIdx.y;                      // 0..27
    const int img = blockIdx.z;                      // 0..63
    const int imgb = img & (NB - 1);
    const int y0 = rp * 2, p0 = rp * 112;
    const int co_w = ch * 128 + w * 32;              // wave's co base

    const float* __restrict__ src = (img < NB ? xsrc : nsrc) + (size_t)imgb * CIN * SP;
    ushort* __restrict__ dh = (img < NB ? h1h : hnh) + (size_t)imgb * COUT * SP;
    ushort* __restrict__ dl = (img < NB ? h1l : hnl) + (size_t)imgb * COUT * SP;

    int sy[4];
    #pragma unroll
    for (int j = 0; j < 4; ++j) sy[j] = (y0 + 55 + j) % 56;   // padded row y0+j

    // ---- stage B once: raw f32 -> split bf16 -> LDS [j][x][ci] swizzled ----
    {
        const int ci = tid >> 2, seg = tid & 3;      // 64 ci x 4 col-segments(14)
        #pragma unroll
        for (int j = 0; j < 4; ++j) {
            const float* r = src + (size_t)ci * SP + sy[j] * 56 + seg * 14;
            #pragma unroll
            for (int c = 0; c < 14; ++c) {
                float v = r[c];
                ushort hi, lo; split_bf(v, hi, lo);
                const int x = seg * 14 + c + 1;      // padded col = orig col + 1
                const int idx = ((j * 58 + x) << 6) + (((ci >> 3) ^ (x & 7)) << 3) + (ci & 7);
                Bh[idx] = hi; Bl[idx] = lo;
            }
        }
        // wrap columns: x=0 <- orig col 55, x=57 <- orig col 0 (512 slots, 2/thr)
        #pragma unroll
        for (int s = 0; s < 2; ++s) {
            const int slot = tid * 2 + s;
            const int j2 = slot >> 7, ci2 = (slot >> 1) & 63, side = slot & 1;
            const float* r2 = src + (size_t)ci2 * SP + sy[j2] * 56;
            const float v = side ? r2[0] : r2[55];
            const int x = side ? 57 : 0;
            ushort hi, lo; split_bf(v, hi, lo);
            const int idx = ((j2 * 58 + x) << 6) + (((ci2 >> 3) ^ (x & 7)) << 3) + (ci2 & 7);
            Bh[idx] = hi; Bl[idx] = lo;
        }
    }
    __syncthreads();                                 // the ONLY barrier

    f32x4 acc[2][7];
    {
        const int rr = (l >> 4) * 4;
        #pragma unroll
        for (int m = 0; m < 2; ++m) {
            const int cb = co_w + 16 * m + rr;
            f32x4 bv = { bias[cb], bias[cb + 1], bias[cb + 2], bias[cb + 3] };
            #pragma unroll
            for (int nf = 0; nf < 7; ++nf) acc[m][nf] = bv;
        }
    }

    // per-nf spatial decomposition (lane-dependent, tap-invariant)
    int b58[7], bx[7];
    #pragma unroll
    for (int nf = 0; nf < 7; ++nf) {
        const int sp = nf * 16 + (l & 15);           // 0..111
        const int ry = (sp >= 56) ? 1 : 0;
        const int xx = sp - ry * 56;
        b58[nf] = ry * 58 + xx;
        bx[nf]  = xx;
    }

    for (int tap = 0; tap < 9; ++tap) {
        const int dy = tap / 3, dx = tap - dy * 3;
        const int toff = dy * 58 + dx;
        #pragma unroll
        for (int ks = 0; ks < 2; ++ks) {
            const int grp = ks * 4 + (l >> 4);
            short8v ah[2], alv[2];
            #pragma unroll
            for (int m = 0; m < 2; ++m) {            // A: direct global gather (L2)
                const int co_l = co_w + 16 * m + (l & 15);
                const size_t off = ((((size_t)(tap * 2 + ks) * 4 + (l >> 4)) * 256 + co_l)) * 8;
                ah[m]  = *(const short8v*)(Wf_hi + off);
                alv[m] = *(const short8v*)(Wf_lo + off);
            }
            #pragma unroll
            for (int nf = 0; nf < 7; ++nf) {
                const int x  = bx[nf] + dx;
                const int bi = ((b58[nf] + toff) << 6) + ((grp ^ (x & 7)) << 3);
                short8v bh  = *(const short8v*)&Bh[bi];
                short8v blv = *(const short8v*)&Bl[bi];
                #pragma unroll
                for (int m = 0; m < 2; ++m) {
                    acc[m][nf] = __builtin_amdgcn_mfma_f32_16x16x32_bf16(ah[m],  bh,  acc[m][nf], 0, 0, 0);
                    acc[m][nf] = __builtin_amdgcn_mfma_f32_16x16x32_bf16(ah[m],  blv, acc[m][nf], 0, 0, 0);
                    acc[m][nf] = __builtin_amdgcn_mfma_f32_16x16x32_bf16(alv[m], bh,  acc[m][nf], 0, 0, 0);
                }
            }
        }
    }

    // epilogue: D row=(l>>4)*4+r -> co, col=l&15 -> sp (verified m89 layout)
    const int rr = (l >> 4) * 4, cc = l & 15;
    #pragma unroll
    for (int m = 0; m < 2; ++m) {
        const int cb = co_w + 16 * m + rr;
        #pragma unroll
        for (int nf = 0; nf < 7; ++nf) {
            const int p = p0 + nf * 16 + cc;
            #pragma unroll
            for (int r = 0; r < 4; ++r) {
                ushort hi, lo; split_bf(acc[m][nf][r], hi, lo);
                dh[(size_t)(cb + r) * SP + p] = hi;
                dl[(size_t)(cb + r) * SP + p] = lo;
            }
        }
    }
}

// ---------------------------------------------------------------------------
// gemm_a_mfma v4: a[b][n][m] = LeakyReLU( sum_k h1[n,k]*hn[m,k] ), bf16x3.
// v3 MINUS the cross-barrier register prefetch (the spill trigger: r11/r12/r15
// all spilled with it; r10/conv/agg all allocate cleanly without it).
// Direct stage: global load -> immediate LDS write (agg's proven skeleton).
// 256 thr = 4 waves (2n x 2m), tile 64n x 64m, grid 512 = 2 blocks/CU (TLP
// hides staging latency). SWZ LDS (measured 0-conflict in r14/r15).
// ---------------------------------------------------------------------------
__global__ __launch_bounds__(256, 2)
void gemm_a_mfma(const ushort* __restrict__ h1h, const ushort* __restrict__ h1l,
                 const ushort* __restrict__ hnh, const ushort* __restrict__ hnl,
                 float* __restrict__ attn)
{
    __shared__ __align__(16) ushort Ah[64][64];
    __shared__ __align__(16) ushort Al[64][64];
    __shared__ __align__(16) ushort Bh[64][64];
    __shared__ __align__(16) ushort Bl[64][64];
    const int tid = threadIdx.x;
    const int w = tid >> 6, l = tid & 63;
    const int wn = w >> 1, wm = w & 1;              // wave grid 2n x 2m
    const int img = blockIdx.x, tile = blockIdx.y;
    const int n0 = (tile & 3) * 64, m0 = (tile >> 2) * 64;

    const ushort* __restrict__ Ahg = h1h + ((size_t)img * COUT + n0) * SP;
    const ushort* __restrict__ Alg = h1l + ((size_t)img * COUT + n0) * SP;
    const ushort* __restrict__ Bhg = hnh + ((size_t)img * COUT + m0) * SP;
    const ushort* __restrict__ Blg = hnl + ((size_t)img * COUT + m0) * SP;

    f32x4 acc[2][2];
    #pragma unroll
    for (int i = 0; i < 2; ++i)
        #pragma unroll
        for (int j = 0; j < 2; ++j) acc[i][j] = (f32x4){0.f, 0.f, 0.f, 0.f};

    // staging: 64 rows x 8 groups x 2 planes per matrix; 256 thr -> 4 uint4
    // for A and 4 for B each, loaded and stored immediately (no held regs).
    const int ap = tid >> 7, arow = (tid & 127) >> 1, ag0 = (tid & 1) * 4;
    const ushort* __restrict__ Asrc = ap ? Alg : Ahg;
    ushort (* __restrict__ Adst)[64] = ap ? Al : Ah;
    const ushort* __restrict__ Bsrc = ap ? Blg : Bhg;
    ushort (* __restrict__ Bdst)[64] = ap ? Bl : Bh;

    const ushort* aptr = Asrc + (size_t)arow * SP + ag0 * 8;
    const ushort* bptr = Bsrc + (size_t)arow * SP + ag0 * 8;

    for (int k0 = 0; k0 < SP; k0 += 64) {
        #pragma unroll
        for (int j = 0; j < 4; ++j) {
            uint4 va = ((const uint4*)(aptr + k0))[j];
            *(uint4*)&Adst[arow][SWZ(arow, ag0 + j)] = va;
            uint4 vb = ((const uint4*)(bptr + k0))[j];
            *(uint4*)&Bdst[arow][SWZ(arow, ag0 + j)] = vb;
        }
        __syncthreads();

        #pragma unroll
        for (int ks = 0; ks < 2; ++ks) {
            const int grp = ks * 4 + (l >> 4);
            short8v ahf[2], alf[2], bhf[2], blf[2];
            #pragma unroll
            for (int i = 0; i < 2; ++i) {
                const int ar_ = 32 * wn + 16 * i + (l & 15);
                ahf[i] = *(const short8v*)&Ah[ar_][SWZ(ar_, grp)];
                alf[i] = *(const short8v*)&Al[ar_][SWZ(ar_, grp)];
                const int br_ = 32 * wm + 16 * i + (l & 15);
                bhf[i] = *(const short8v*)&Bh[br_][SWZ(br_, grp)];
                blf[i] = *(const short8v*)&Bl[br_][SWZ(br_, grp)];
            }
            #pragma unroll
            for (int i = 0; i < 2; ++i)
                #pragma unroll
                for (int j = 0; j < 2; ++j) {
                    acc[i][j] = __builtin_amdgcn_mfma_f32_16x16x32_bf16(ahf[i], bhf[j], acc[i][j], 0, 0, 0);
                    acc[i][j] = __builtin_amdgcn_mfma_f32_16x16x32_bf16(ahf[i], blf[j], acc[i][j], 0, 0, 0);
                    acc[i][j] = __builtin_amdgcn_mfma_f32_16x16x32_bf16(alf[i], bhf[j], acc[i][j], 0, 0, 0);
                }
        }
        __syncthreads();
    }

    const int rr = (l >> 4) * 4, cc = l & 15;
    float* __restrict__ aimg = attn + (size_t)img * COUT * COUT;
    #pragma unroll
    for (int i = 0; i < 2; ++i) {
        const int nb = n0 + 32 * wn + 16 * i + rr;
        #pragma unroll
        for (int j = 0; j < 2; ++j) {
            const int m = m0 + 32 * wm + 16 * j + cc;
            #pragma unroll
            for (int r = 0; r < 4; ++r) {
                float v = acc[i][j][r];
                v = (v >= 0.f) ? v : NEG_SLOPE * v;
                aimg[(size_t)(nb + r) * COUT + m] = v;
            }
        }
    }
}

// ---------------------------------------------------------------------------
// softmax over axis n (dim=1) per (b,m) column, in place. (unchanged)
// ---------------------------------------------------------------------------
__global__ __launch_bounds__(64)
void softmax_k(float* __restrict__ attn)
{
    const int b = blockIdx.y;
    const int m = blockIdx.x * 64 + threadIdx.x;
    float* a = attn + (size_t)b * COUT * COUT;
    float mx = -1e30f;
    for (int n_ = 0; n_ < COUT; ++n_) mx = fmaxf(mx, a[n_ * COUT + m]);
    float s = 0.f;
    for (int n_ = 0; n_ < COUT; ++n_) s += expf(a[n_ * COUT + m] - mx);
    float inv = 1.f / s;
    for (int n_ = 0; n_ < COUT; ++n_)
        a[n_ * COUT + m] = expf(a[n_ * COUT + m] - mx) * inv;
}

// ---------------------------------------------------------------------------
// gemm_agg_mfma: out[n][f] = 0.1 * sum_m attn[n][m]*h1[m][f] + 0.9 * h1[n][f]
// (unchanged from round 9/10 — 68 VGPR, no spill)
// ---------------------------------------------------------------------------
__global__ __launch_bounds__(256, 2)
void gemm_agg_mfma(const float* __restrict__ attn,
                   const ushort* __restrict__ h1h, const ushort* __restrict__ h1l,
                   float* __restrict__ out)
{
    __shared__ __align__(16) ushort Ah[128][72];
    __shared__ __align__(16) ushort Al[128][72];
    __shared__ __align__(16) ushort Bh[112][72];
    __shared__ __align__(16) ushort Bl[112][72];
    const int tid = threadIdx.x, w = tid >> 6, l = tid & 63;
    const int f0 = blockIdx.x * 112;
    const int n0 = blockIdx.y * 128;
    const int img = blockIdx.z;

    const float*  __restrict__ A  = attn + (size_t)img * COUT * COUT;
    const ushort* __restrict__ Hh = h1h + (size_t)img * COUT * SP;
    const ushort* __restrict__ Hl = h1l + (size_t)img * COUT * SP;

    f32x4 acc[2][7];
    #pragma unroll
    for (int nf = 0; nf < 2; ++nf)
        #pragma unroll
        for (int mf = 0; mf < 7; ++mf) acc[nf][mf] = (f32x4){0.f, 0.f, 0.f, 0.f};

    const int ar = tid >> 1, ac = (tid & 1) * 32;
    const int bp = tid >> 7, bm = (tid & 127) >> 1, bf = (tid & 1) * 56;
    const ushort* __restrict__ Bsrc = bp ? Hl : Hh;
    ushort (* __restrict__ Bdst)[72] = bp ? Bl : Bh;

    for (int k0 = 0; k0 < COUT; k0 += 64) {
        {
            const float* g = A + (size_t)(n0 + ar) * COUT + k0 + ac;
            uint* dh = (uint*)&Ah[ar][ac];
            uint* dl = (uint*)&Al[ar][ac];
            #pragma unroll
            for (int q = 0; q < 8; ++q) {
                float4 v = *(const float4*)(g + 4 * q);
                ushort h0, l0, h1_, l1_, h2, l2, h3, l3;
                split_bf(v.x, h0, l0); split_bf(v.y, h1_, l1_);
                split_bf(v.z, h2, l2); split_bf(v.w, h3, l3);
                dh[2 * q]     = (uint)h0 | ((uint)h1_ << 16);
                dh[2 * q + 1] = (uint)h2 | ((uint)h3  << 16);
                dl[2 * q]     = (uint)l0 | ((uint)l1_ << 16);
                dl[2 * q + 1] = (uint)l2 | ((uint)l3  << 16);
            }
        }
        {
            const ushort* g = Bsrc + (size_t)(k0 + bm) * SP + f0 + bf;
            #pragma unroll
            for (int q = 0; q < 7; ++q) {
                uint4 v = *(const uint4*)(g + 8 * q);
                const ushort* vp = (const ushort*)&v;
                #pragma unroll
                for (int e = 0; e < 8; ++e)
                    Bdst[bf + 8 * q + e][bm] = vp[e];
            }
        }
        __syncthreads();
        #pragma unroll
        for (int ks = 0; ks < 2; ++ks) {
            const int kb = ks * 32 + (l >> 4) * 8;
            short8v ah[2], alv[2];
            #pragma unroll
            for (int nf = 0; nf < 2; ++nf) {
                const int row = 32 * w + 16 * nf + (l & 15);
                ah[nf]  = *(const short8v*)&Ah[row][kb];
                alv[nf] = *(const short8v*)&Al[row][kb];
            }
            #pragma unroll
            for (int mf = 0; mf < 7; ++mf) {
                const int br = mf * 16 + (l & 15);
                short8v bh  = *(const short8v*)&Bh[br][kb];
                short8v blv = *(const short8v*)&Bl[br][kb];
                #pragma unroll
                for (int nf = 0; nf < 2; ++nf) {
                    acc[nf][mf] = __builtin_amdgcn_mfma_f32_16x16x32_bf16(ah[nf],  bh,  acc[nf][mf], 0, 0, 0);
                    acc[nf][mf] = __builtin_amdgcn_mfma_f32_16x16x32_bf16(ah[nf],  blv, acc[nf][mf], 0, 0, 0);
                    acc[nf][mf] = __builtin_amdgcn_mfma_f32_16x16x32_bf16(alv[nf], bh,  acc[nf][mf], 0, 0, 0);
                }
            }
        }
        __syncthreads();
    }

    const int rr = (l >> 4) * 4, cc = l & 15;
    float* __restrict__ orow = out + (size_t)img * COUT * SP;
    #pragma unroll
    for (int nf = 0; nf < 2; ++nf) {
        const int nb = n0 + 32 * w + 16 * nf + rr;
        #pragma unroll
        for (int mf = 0; mf < 7; ++mf) {
            const int f = f0 + 16 * mf + cc;
            #pragma unroll
            for (int r = 0; r < 4; ++r) {
                const int n = nb + r;
                float h = bfr(Hh[(size_t)n * SP + f]) + bfr(Hl[(size_t)n * SP + f]);
                orow[(size_t)n * SP + f] = 0.1f * acc[nf][mf][r] + 0.9f * h;
            }
        }
    }
}

// ---------------------------------------------------------------------------
extern "C" void kernel_launch(void* const* d_in, const int* in_sizes, int n_in,
                              void* d_out, int out_size, void* d_ws, size_t ws_size,
                              hipStream_t stream)
{
    const float* x    = (const float*)d_in[0];
    const float* nn   = (const float*)d_in[1];
    const float* W    = (const float*)d_in[2];
    const float* bias = (const float*)d_in[3];
    float* out = (float*)d_out;

    // ws (111.2 MB): h1b_hi (51.4) | h1b_lo (51.4) | zone (8.39):
    //   conv phase: Wf hi/lo (1.2 MB); gemm phase: attn f32 (overlaps dead Wf).
    ushort* h1b_hi = (ushort*)d_ws;
    ushort* h1b_lo = h1b_hi + (size_t)NB * COUT * SP;
    char*   zone   = (char*)(h1b_lo + (size_t)NB * COUT * SP);
    ushort* Wf_hi  = (ushort*)zone;
    ushort* Wf_lo  = Wf_hi + 9 * 256 * 64;
    float*  attn   = (float*)zone;          // overwrites Wf after convs complete
    // d_out (102.8 MB): hnb_hi | hnb_lo until gemm_agg_mfma overwrites with out f32.
    ushort* hnb_hi = (ushort*)d_out;
    ushort* hnb_lo = hnb_hi + (size_t)NB * COUT * SP;

    pack_w    <<<576, 256, 0, stream>>>(W, Wf_hi, Wf_lo);
    conv_fused<<<dim3(2, 28, 2 * NB), 256, 0, stream>>>(x, nn, Wf_hi, Wf_lo, bias,
                                                        h1b_hi, h1b_lo, hnb_hi, hnb_lo);
    gemm_a_mfma  <<<dim3(32, 16),    256, 0, stream>>>(h1b_hi, h1b_lo, hnb_hi, hnb_lo, attn);
    softmax_k    <<<dim3(4, NB),     64,  0, stream>>>(attn);
    gemm_agg_mfma<<<dim3(28, 2, NB), 256, 0, stream>>>(attn, h1b_hi, h1b_lo, out);
}

// Round 17
// 388.586 us; speedup vs baseline: 1.6909x; 1.0517x over previous
//
#include <hip/hip_runtime.h>
#include <hip/hip_bf16.h>
#include <cstddef>

#define SP 3136          // 56*56
#define CIN 64
#define COUT 256
#define NB 32
#define NEG_SLOPE 0.01f

typedef __attribute__((ext_vector_type(8))) short short8v;  // 8 bf16 (4 VGPRs)
typedef __attribute__((ext_vector_type(4))) float f32x4;    // MFMA accumulator

__device__ __forceinline__ float bfr(ushort h) {
    union { uint u; float f; } c; c.u = ((uint)h) << 16; return c.f;
}
__device__ __forceinline__ void split_bf(float v, ushort& hi, ushort& lo) {
    __hip_bfloat16 h = __float2bfloat16(v);
    float r = v - __bfloat162float(h);
    __hip_bfloat16 l2 = __float2bfloat16(r);
    hi = *(ushort*)&h; lo = *(ushort*)&l2;
}

// XOR swizzle: logical 8-ushort group g of row -> physical ushort offset
#define SWZ(row, g) ((((g) ^ ((row) & 7))) * 8)

// ---------------------------------------------------------------------------
// pack_w: W[co][ci][ky][kx] f32 -> fragment-contiguous planes (unchanged)
// ---------------------------------------------------------------------------
__global__ __launch_bounds__(256)
void pack_w(const float* __restrict__ W, ushort* __restrict__ wh, ushort* __restrict__ wl)
{
    const int id = blockIdx.x * 256 + threadIdx.x;   // 147456 = 9*256*64
    const int ci = id & 63, co = (id >> 6) & 255, tap = id >> 14;
    float v = W[(size_t)(co * 64 + ci) * 9 + tap];
    ushort hi, lo; split_bf(v, hi, lo);
    const int ks = ci >> 5, cig = (ci >> 3) & 3, ce = ci & 7;
    const size_t o = (((size_t)(tap * 2 + ks) * 4 + cig) * 256 + co) * 8 + ce;
    wh[o] = hi; wl[o] = lo;
}

// ---------------------------------------------------------------------------
// conv_fused v3: 3x3 circular conv, bf16x3 MFMA, barrier-free tap loop.
// r16 change: wave co-tile 32 -> 64 (acc[2][7] -> acc[4][7]); one block now
// covers ALL 256 co -> half as many waves read each B tile (B LDS traffic
// halved; LDS drops off the critical path) and input staged once per rp
// (FETCH halved). Grid (28 rp, 64 img), 256 thr = 4 waves x (64co x 112sp).
// ---------------------------------------------------------------------------
__global__ __launch_bounds__(256, 2)
void conv_fused(const float* __restrict__ xsrc, const float* __restrict__ nsrc,
                const ushort* __restrict__ Wf_hi, const ushort* __restrict__ Wf_lo,
                const float* __restrict__ bias,
                ushort* __restrict__ h1h, ushort* __restrict__ h1l,
                ushort* __restrict__ hnh, ushort* __restrict__ hnl)
{
    __shared__ __align__(16) ushort Bh[4 * 58 * 64]; // 29 KB
    __shared__ __align__(16) ushort Bl[4 * 58 * 64]; // 29 KB
    const int tid = threadIdx.x;
    const int w = tid >> 6, l = tid & 63;
    const int rp  = blockIdx.x;                      // 0..27
    const int img = blockIdx.y;                      // 0..63
    const int imgb = img & (NB - 1);
    const int y0 = rp * 2, p0 = rp * 112;
    const int co_w = w * 64;                         // wave's co base (4x64=256)

    const float* __restrict__ src = (img < NB ? xsrc : nsrc) + (size_t)imgb * CIN * SP;
    ushort* __restrict__ dh = (img < NB ? h1h : hnh) + (size_t)imgb * COUT * SP;
    ushort* __restrict__ dl = (img < NB ? h1l : hnl) + (size_t)imgb * COUT * SP;

    int sy[4];
    #pragma unroll
    for (int j = 0; j < 4; ++j) sy[j] = (y0 + 55 + j) % 56;   // padded row y0+j

    // ---- stage B once: raw f32 -> split bf16 -> LDS [j][x][ci] swizzled ----
    {
        const int ci = tid >> 2, seg = tid & 3;      // 64 ci x 4 col-segments(14)
        #pragma unroll
        for (int j = 0; j < 4; ++j) {
            const float* r = src + (size_t)ci * SP + sy[j] * 56 + seg * 14;
            #pragma unroll
            for (int c = 0; c < 14; ++c) {
                float v = r[c];
                ushort hi, lo; split_bf(v, hi, lo);
                const int x = seg * 14 + c + 1;      // padded col = orig col + 1
                const int idx = ((j * 58 + x) << 6) + (((ci >> 3) ^ (x & 7)) << 3) + (ci & 7);
                Bh[idx] = hi; Bl[idx] = lo;
            }
        }
        // wrap columns: x=0 <- orig col 55, x=57 <- orig col 0 (512 slots, 2/thr)
        #pragma unroll
        for (int s = 0; s < 2; ++s) {
            const int slot = tid * 2 + s;
            const int j2 = slot >> 7, ci2 = (slot >> 1) & 63, side = slot & 1;
            const float* r2 = src + (size_t)ci2 * SP + sy[j2] * 56;
            const float v = side ? r2[0] : r2[55];
            const int x = side ? 57 : 0;
            ushort hi, lo; split_bf(v, hi, lo);
            const int idx = ((j2 * 58 + x) << 6) + (((ci2 >> 3) ^ (x & 7)) << 3) + (ci2 & 7);
            Bh[idx] = hi; Bl[idx] = lo;
        }
    }
    __syncthreads();                                 // the ONLY barrier

    f32x4 acc[4][7];
    {
        const int rr = (l >> 4) * 4;
        #pragma unroll
        for (int m = 0; m < 4; ++m) {
            const int cb = co_w + 16 * m + rr;
            f32x4 bv = { bias[cb], bias[cb + 1], bias[cb + 2], bias[cb + 3] };
            #pragma unroll
            for (int nf = 0; nf < 7; ++nf) acc[m][nf] = bv;
        }
    }

    // per-nf spatial decomposition (lane-dependent, tap-invariant)
    int b58[7], bx[7];
    #pragma unroll
    for (int nf = 0; nf < 7; ++nf) {
        const int sp = nf * 16 + (l & 15);           // 0..111
        const int ry = (sp >= 56) ? 1 : 0;
        const int xx = sp - ry * 56;
        b58[nf] = ry * 58 + xx;
        bx[nf]  = xx;
    }

    for (int tap = 0; tap < 9; ++tap) {
        const int dy = tap / 3, dx = tap - dy * 3;
        const int toff = dy * 58 + dx;
        #pragma unroll
        for (int ks = 0; ks < 2; ++ks) {
            const int grp = ks * 4 + (l >> 4);
            short8v ah[4], alv[4];
            #pragma unroll
            for (int m = 0; m < 4; ++m) {            // A: direct global gather (L2)
                const int co_l = co_w + 16 * m + (l & 15);
                const size_t off = ((((size_t)(tap * 2 + ks) * 4 + (l >> 4)) * 256 + co_l)) * 8;
                ah[m]  = *(const short8v*)(Wf_hi + off);
                alv[m] = *(const short8v*)(Wf_lo + off);
            }
            #pragma unroll
            for (int nf = 0; nf < 7; ++nf) {
                const int x  = bx[nf] + dx;
                const int bi = ((b58[nf] + toff) << 6) + ((grp ^ (x & 7)) << 3);
                short8v bh  = *(const short8v*)&Bh[bi];
                short8v blv = *(const short8v*)&Bl[bi];
                #pragma unroll
                for (int m = 0; m < 4; ++m) {
                    acc[m][nf] = __builtin_amdgcn_mfma_f32_16x16x32_bf16(ah[m],  bh,  acc[m][nf], 0, 0, 0);
                    acc[m][nf] = __builtin_amdgcn_mfma_f32_16x16x32_bf16(ah[m],  blv, acc[m][nf], 0, 0, 0);
                    acc[m][nf] = __builtin_amdgcn_mfma_f32_16x16x32_bf16(alv[m], bh,  acc[m][nf], 0, 0, 0);
                }
            }
        }
    }

    // epilogue: D row=(l>>4)*4+r -> co, col=l&15 -> sp (verified m89 layout)
    const int rr = (l >> 4) * 4, cc = l & 15;
    #pragma unroll
    for (int m = 0; m < 4; ++m) {
        const int cb = co_w + 16 * m + rr;
        #pragma unroll
        for (int nf = 0; nf < 7; ++nf) {
            const int p = p0 + nf * 16 + cc;
            #pragma unroll
            for (int r = 0; r < 4; ++r) {
                ushort hi, lo; split_bf(acc[m][nf][r], hi, lo);
                dh[(size_t)(cb + r) * SP + p] = hi;
                dl[(size_t)(cb + r) * SP + p] = lo;
            }
        }
    }
}

// ---------------------------------------------------------------------------
// gemm_a_mfma v4 (unchanged from round 16 — direct stage, no cross-barrier
// prefetch, SWZ LDS; measured off top-5)
// ---------------------------------------------------------------------------
__global__ __launch_bounds__(256, 2)
void gemm_a_mfma(const ushort* __restrict__ h1h, const ushort* __restrict__ h1l,
                 const ushort* __restrict__ hnh, const ushort* __restrict__ hnl,
                 float* __restrict__ attn)
{
    __shared__ __align__(16) ushort Ah[64][64];
    __shared__ __align__(16) ushort Al[64][64];
    __shared__ __align__(16) ushort Bh[64][64];
    __shared__ __align__(16) ushort Bl[64][64];
    const int tid = threadIdx.x;
    const int w = tid >> 6, l = tid & 63;
    const int wn = w >> 1, wm = w & 1;              // wave grid 2n x 2m
    const int img = blockIdx.x, tile = blockIdx.y;
    const int n0 = (tile & 3) * 64, m0 = (tile >> 2) * 64;

    const ushort* __restrict__ Ahg = h1h + ((size_t)img * COUT + n0) * SP;
    const ushort* __restrict__ Alg = h1l + ((size_t)img * COUT + n0) * SP;
    const ushort* __restrict__ Bhg = hnh + ((size_t)img * COUT + m0) * SP;
    const ushort* __restrict__ Blg = hnl + ((size_t)img * COUT + m0) * SP;

    f32x4 acc[2][2];
    #pragma unroll
    for (int i = 0; i < 2; ++i)
        #pragma unroll
        for (int j = 0; j < 2; ++j) acc[i][j] = (f32x4){0.f, 0.f, 0.f, 0.f};

    const int ap = tid >> 7, arow = (tid & 127) >> 1, ag0 = (tid & 1) * 4;
    const ushort* __restrict__ Asrc = ap ? Alg : Ahg;
    ushort (* __restrict__ Adst)[64] = ap ? Al : Ah;
    const ushort* __restrict__ Bsrc = ap ? Blg : Bhg;
    ushort (* __restrict__ Bdst)[64] = ap ? Bl : Bh;

    const ushort* aptr = Asrc + (size_t)arow * SP + ag0 * 8;
    const ushort* bptr = Bsrc + (size_t)arow * SP + ag0 * 8;

    for (int k0 = 0; k0 < SP; k0 += 64) {
        #pragma unroll
        for (int j = 0; j < 4; ++j) {
            uint4 va = ((const uint4*)(aptr + k0))[j];
            *(uint4*)&Adst[arow][SWZ(arow, ag0 + j)] = va;
            uint4 vb = ((const uint4*)(bptr + k0))[j];
            *(uint4*)&Bdst[arow][SWZ(arow, ag0 + j)] = vb;
        }
        __syncthreads();

        #pragma unroll
        for (int ks = 0; ks < 2; ++ks) {
            const int grp = ks * 4 + (l >> 4);
            short8v ahf[2], alf[2], bhf[2], blf[2];
            #pragma unroll
            for (int i = 0; i < 2; ++i) {
                const int ar_ = 32 * wn + 16 * i + (l & 15);
                ahf[i] = *(const short8v*)&Ah[ar_][SWZ(ar_, grp)];
                alf[i] = *(const short8v*)&Al[ar_][SWZ(ar_, grp)];
                const int br_ = 32 * wm + 16 * i + (l & 15);
                bhf[i] = *(const short8v*)&Bh[br_][SWZ(br_, grp)];
                blf[i] = *(const short8v*)&Bl[br_][SWZ(br_, grp)];
            }
            #pragma unroll
            for (int i = 0; i < 2; ++i)
                #pragma unroll
                for (int j = 0; j < 2; ++j) {
                    acc[i][j] = __builtin_amdgcn_mfma_f32_16x16x32_bf16(ahf[i], bhf[j], acc[i][j], 0, 0, 0);
                    acc[i][j] = __builtin_amdgcn_mfma_f32_16x16x32_bf16(ahf[i], blf[j], acc[i][j], 0, 0, 0);
                    acc[i][j] = __builtin_amdgcn_mfma_f32_16x16x32_bf16(alf[i], bhf[j], acc[i][j], 0, 0, 0);
                }
        }
        __syncthreads();
    }

    const int rr = (l >> 4) * 4, cc = l & 15;
    float* __restrict__ aimg = attn + (size_t)img * COUT * COUT;
    #pragma unroll
    for (int i = 0; i < 2; ++i) {
        const int nb = n0 + 32 * wn + 16 * i + rr;
        #pragma unroll
        for (int j = 0; j < 2; ++j) {
            const int m = m0 + 32 * wm + 16 * j + cc;
            #pragma unroll
            for (int r = 0; r < 4; ++r) {
                float v = acc[i][j][r];
                v = (v >= 0.f) ? v : NEG_SLOPE * v;
                aimg[(size_t)(nb + r) * COUT + m] = v;
            }
        }
    }
}

// ---------------------------------------------------------------------------
// softmax over axis n (dim=1) per (b,m) column, in place. (unchanged)
// ---------------------------------------------------------------------------
__global__ __launch_bounds__(64)
void softmax_k(float* __restrict__ attn)
{
    const int b = blockIdx.y;
    const int m = blockIdx.x * 64 + threadIdx.x;
    float* a = attn + (size_t)b * COUT * COUT;
    float mx = -1e30f;
    for (int n_ = 0; n_ < COUT; ++n_) mx = fmaxf(mx, a[n_ * COUT + m]);
    float s = 0.f;
    for (int n_ = 0; n_ < COUT; ++n_) s += expf(a[n_ * COUT + m] - mx);
    float inv = 1.f / s;
    for (int n_ = 0; n_ < COUT; ++n_)
        a[n_ * COUT + m] = expf(a[n_ * COUT + m] - mx) * inv;
}

// ---------------------------------------------------------------------------
// gemm_agg_mfma: out[n][f] = 0.1 * sum_m attn[n][m]*h1[m][f] + 0.9 * h1[n][f]
// (unchanged — 68 VGPR, no spill)
// ---------------------------------------------------------------------------
__global__ __launch_bounds__(256, 2)
void gemm_agg_mfma(const float* __restrict__ attn,
                   const ushort* __restrict__ h1h, const ushort* __restrict__ h1l,
                   float* __restrict__ out)
{
    __shared__ __align__(16) ushort Ah[128][72];
    __shared__ __align__(16) ushort Al[128][72];
    __shared__ __align__(16) ushort Bh[112][72];
    __shared__ __align__(16) ushort Bl[112][72];
    const int tid = threadIdx.x, w = tid >> 6, l = tid & 63;
    const int f0 = blockIdx.x * 112;
    const int n0 = blockIdx.y * 128;
    const int img = blockIdx.z;

    const float*  __restrict__ A  = attn + (size_t)img * COUT * COUT;
    const ushort* __restrict__ Hh = h1h + (size_t)img * COUT * SP;
    const ushort* __restrict__ Hl = h1l + (size_t)img * COUT * SP;

    f32x4 acc[2][7];
    #pragma unroll
    for (int nf = 0; nf < 2; ++nf)
        #pragma unroll
        for (int mf = 0; mf < 7; ++mf) acc[nf][mf] = (f32x4){0.f, 0.f, 0.f, 0.f};

    const int ar = tid >> 1, ac = (tid & 1) * 32;
    const int bp = tid >> 7, bm = (tid & 127) >> 1, bf = (tid & 1) * 56;
    const ushort* __restrict__ Bsrc = bp ? Hl : Hh;
    ushort (* __restrict__ Bdst)[72] = bp ? Bl : Bh;

    for (int k0 = 0; k0 < COUT; k0 += 64) {
        {
            const float* g = A + (size_t)(n0 + ar) * COUT + k0 + ac;
            uint* dh = (uint*)&Ah[ar][ac];
            uint* dl = (uint*)&Al[ar][ac];
            #pragma unroll
            for (int q = 0; q < 8; ++q) {
                float4 v = *(const float4*)(g + 4 * q);
                ushort h0, l0, h1_, l1_, h2, l2, h3, l3;
                split_bf(v.x, h0, l0); split_bf(v.y, h1_, l1_);
                split_bf(v.z, h2, l2); split_bf(v.w, h3, l3);
                dh[2 * q]     = (uint)h0 | ((uint)h1_ << 16);
                dh[2 * q + 1] = (uint)h2 | ((uint)h3  << 16);
                dl[2 * q]     = (uint)l0 | ((uint)l1_ << 16);
                dl[2 * q + 1] = (uint)l2 | ((uint)l3  << 16);
            }
        }
        {
            const ushort* g = Bsrc + (size_t)(k0 + bm) * SP + f0 + bf;
            #pragma unroll
            for (int q = 0; q < 7; ++q) {
                uint4 v = *(const uint4*)(g + 8 * q);
                const ushort* vp = (const ushort*)&v;
                #pragma unroll
                for (int e = 0; e < 8; ++e)
                    Bdst[bf + 8 * q + e][bm] = vp[e];
            }
        }
        __syncthreads();
        #pragma unroll
        for (int ks = 0; ks < 2; ++ks) {
            const int kb = ks * 32 + (l >> 4) * 8;
            short8v ah[2], alv[2];
            #pragma unroll
            for (int nf = 0; nf < 2; ++nf) {
                const int row = 32 * w + 16 * nf + (l & 15);
                ah[nf]  = *(const short8v*)&Ah[row][kb];
                alv[nf] = *(const short8v*)&Al[row][kb];
            }
            #pragma unroll
            for (int mf = 0; mf < 7; ++mf) {
                const int br = mf * 16 + (l & 15);
                short8v bh  = *(const short8v*)&Bh[br][kb];
                short8v blv = *(const short8v*)&Bl[br][kb];
                #pragma unroll
                for (int nf = 0; nf < 2; ++nf) {
                    acc[nf][mf] = __builtin_amdgcn_mfma_f32_16x16x32_bf16(ah[nf],  bh,  acc[nf][mf], 0, 0, 0);
                    acc[nf][mf] = __builtin_amdgcn_mfma_f32_16x16x32_bf16(ah[nf],  blv, acc[nf][mf], 0, 0, 0);
                    acc[nf][mf] = __builtin_amdgcn_mfma_f32_16x16x32_bf16(alv[nf], bh,  acc[nf][mf], 0, 0, 0);
                }
            }
        }
        __syncthreads();
    }

    const int rr = (l >> 4) * 4, cc = l & 15;
    float* __restrict__ orow = out + (size_t)img * COUT * SP;
    #pragma unroll
    for (int nf = 0; nf < 2; ++nf) {
        const int nb = n0 + 32 * w + 16 * nf + rr;
        #pragma unroll
        for (int mf = 0; mf < 7; ++mf) {
            const int f = f0 + 16 * mf + cc;
            #pragma unroll
            for (int r = 0; r < 4; ++r) {
                const int n = nb + r;
                float h = bfr(Hh[(size_t)n * SP + f]) + bfr(Hl[(size_t)n * SP + f]);
                orow[(size_t)n * SP + f] = 0.1f * acc[nf][mf][r] + 0.9f * h;
            }
        }
    }
}

// ---------------------------------------------------------------------------
extern "C" void kernel_launch(void* const* d_in, const int* in_sizes, int n_in,
                              void* d_out, int out_size, void* d_ws, size_t ws_size,
                              hipStream_t stream)
{
    const float* x    = (const float*)d_in[0];
    const float* nn   = (const float*)d_in[1];
    const float* W    = (const float*)d_in[2];
    const float* bias = (const float*)d_in[3];
    float* out = (float*)d_out;

    // ws (111.2 MB): h1b_hi (51.4) | h1b_lo (51.4) | zone (8.39):
    //   conv phase: Wf hi/lo (1.2 MB); gemm phase: attn f32 (overlaps dead Wf).
    ushort* h1b_hi = (ushort*)d_ws;
    ushort* h1b_lo = h1b_hi + (size_t)NB * COUT * SP;
    char*   zone   = (char*)(h1b_lo + (size_t)NB * COUT * SP);
    ushort* Wf_hi  = (ushort*)zone;
    ushort* Wf_lo  = Wf_hi + 9 * 256 * 64;
    float*  attn   = (float*)zone;          // overwrites Wf after convs complete
    // d_out (102.8 MB): hnb_hi | hnb_lo until gemm_agg_mfma overwrites with out f32.
    ushort* hnb_hi = (ushort*)d_out;
    ushort* hnb_lo = hnb_hi + (size_t)NB * COUT * SP;

    pack_w    <<<576, 256, 0, stream>>>(W, Wf_hi, Wf_lo);
    conv_fused<<<dim3(28, 2 * NB), 256, 0, stream>>>(x, nn, Wf_hi, Wf_lo, bias,
                                                     h1b_hi, h1b_lo, hnb_hi, hnb_lo);
    gemm_a_mfma  <<<dim3(32, 16),    256, 0, stream>>>(h1b_hi, h1b_lo, hnb_hi, hnb_lo, attn);
    softmax_k    <<<dim3(4, NB),     64,  0, stream>>>(attn);
    gemm_agg_mfma<<<dim3(28, 2, NB), 256, 0, stream>>>(attn, h1b_hi, h1b_lo, out);
}

// Round 18
// 365.563 us; speedup vs baseline: 1.7974x; 1.0630x over previous
//
#include <hip/hip_runtime.h>
#include <hip/hip_bf16.h>
#include <cstddef>

#define SP 3136          // 56*56
#define CIN 64
#define COUT 256
#define NB 32
#define NEG_SLOPE 0.01f

typedef __attribute__((ext_vector_type(8))) short short8v;  // 8 bf16 (4 VGPRs)
typedef __attribute__((ext_vector_type(4))) float f32x4;    // MFMA accumulator

__device__ __forceinline__ float bfr(ushort h) {
    union { uint u; float f; } c; c.u = ((uint)h) << 16; return c.f;
}
__device__ __forceinline__ void split_bf(float v, ushort& hi, ushort& lo) {
    __hip_bfloat16 h = __float2bfloat16(v);
    float r = v - __bfloat162float(h);
    __hip_bfloat16 l2 = __float2bfloat16(r);
    hi = *(ushort*)&h; lo = *(ushort*)&l2;
}

// XOR swizzle: logical 8-ushort group g of row -> physical ushort offset
#define SWZ(row, g) ((((g) ^ ((row) & 7))) * 8)

// ---------------------------------------------------------------------------
// pack_w: W[co][ci][ky][kx] f32 -> fragment-contiguous planes (unchanged)
// ---------------------------------------------------------------------------
__global__ __launch_bounds__(256)
void pack_w(const float* __restrict__ W, ushort* __restrict__ wh, ushort* __restrict__ wl)
{
    const int id = blockIdx.x * 256 + threadIdx.x;   // 147456 = 9*256*64
    const int ci = id & 63, co = (id >> 6) & 255, tap = id >> 14;
    float v = W[(size_t)(co * 64 + ci) * 9 + tap];
    ushort hi, lo; split_bf(v, hi, lo);
    const int ks = ci >> 5, cig = (ci >> 3) & 3, ce = ci & 7;
    const size_t o = (((size_t)(tap * 2 + ks) * 4 + cig) * 256 + co) * 8 + ce;
    wh[o] = hi; wl[o] = lo;
}

// ---------------------------------------------------------------------------
// conv_fused v4: 3x3 circular conv, bf16x3 MFMA, barrier-free tap loop.
// r17 change: software-pipelined A-gather — flattened 18-iter (tap,ks) loop
// prefetches next iter's 8 A-fragments during current MFMA burst (legal:
// no barrier in the loop, so no cross-barrier live range -> no spill per the
// r15/r16-established model). A addressing strength-reduced to base+it*8192.
// ---------------------------------------------------------------------------
__global__ __launch_bounds__(256, 2)
void conv_fused(const float* __restrict__ xsrc, const float* __restrict__ nsrc,
                const ushort* __restrict__ Wf_hi, const ushort* __restrict__ Wf_lo,
                const float* __restrict__ bias,
                ushort* __restrict__ h1h, ushort* __restrict__ h1l,
                ushort* __restrict__ hnh, ushort* __restrict__ hnl)
{
    __shared__ __align__(16) ushort Bh[4 * 58 * 64]; // 29 KB
    __shared__ __align__(16) ushort Bl[4 * 58 * 64]; // 29 KB
    const int tid = threadIdx.x;
    const int w = tid >> 6, l = tid & 63;
    const int rp  = blockIdx.x;                      // 0..27
    const int img = blockIdx.y;                      // 0..63
    const int imgb = img & (NB - 1);
    const int y0 = rp * 2, p0 = rp * 112;
    const int co_w = w * 64;                         // wave's co base (4x64=256)

    const float* __restrict__ src = (img < NB ? xsrc : nsrc) + (size_t)imgb * CIN * SP;
    ushort* __restrict__ dh = (img < NB ? h1h : hnh) + (size_t)imgb * COUT * SP;
    ushort* __restrict__ dl = (img < NB ? h1l : hnl) + (size_t)imgb * COUT * SP;

    int sy[4];
    #pragma unroll
    for (int j = 0; j < 4; ++j) sy[j] = (y0 + 55 + j) % 56;   // padded row y0+j

    // ---- stage B once: raw f32 -> split bf16 -> LDS [j][x][ci] swizzled ----
    {
        const int ci = tid >> 2, seg = tid & 3;      // 64 ci x 4 col-segments(14)
        #pragma unroll
        for (int j = 0; j < 4; ++j) {
            const float* r = src + (size_t)ci * SP + sy[j] * 56 + seg * 14;
            #pragma unroll
            for (int c = 0; c < 14; ++c) {
                float v = r[c];
                ushort hi, lo; split_bf(v, hi, lo);
                const int x = seg * 14 + c + 1;      // padded col = orig col + 1
                const int idx = ((j * 58 + x) << 6) + (((ci >> 3) ^ (x & 7)) << 3) + (ci & 7);
                Bh[idx] = hi; Bl[idx] = lo;
            }
        }
        // wrap columns: x=0 <- orig col 55, x=57 <- orig col 0 (512 slots, 2/thr)
        #pragma unroll
        for (int s = 0; s < 2; ++s) {
            const int slot = tid * 2 + s;
            const int j2 = slot >> 7, ci2 = (slot >> 1) & 63, side = slot & 1;
            const float* r2 = src + (size_t)ci2 * SP + sy[j2] * 56;
            const float v = side ? r2[0] : r2[55];
            const int x = side ? 57 : 0;
            ushort hi, lo; split_bf(v, hi, lo);
            const int idx = ((j2 * 58 + x) << 6) + (((ci2 >> 3) ^ (x & 7)) << 3) + (ci2 & 7);
            Bh[idx] = hi; Bl[idx] = lo;
        }
    }
    __syncthreads();                                 // the ONLY barrier

    f32x4 acc[4][7];
    {
        const int rr = (l >> 4) * 4;
        #pragma unroll
        for (int m = 0; m < 4; ++m) {
            const int cb = co_w + 16 * m + rr;
            f32x4 bv = { bias[cb], bias[cb + 1], bias[cb + 2], bias[cb + 3] };
            #pragma unroll
            for (int nf = 0; nf < 7; ++nf) acc[m][nf] = bv;
        }
    }

    // per-nf spatial decomposition (lane-dependent, tap-invariant)
    int b58[7], bx[7];
    #pragma unroll
    for (int nf = 0; nf < 7; ++nf) {
        const int sp = nf * 16 + (l & 15);           // 0..111
        const int ry = (sp >= 56) ? 1 : 0;
        const int xx = sp - ry * 56;
        b58[nf] = ry * 58 + xx;
        bx[nf]  = xx;
    }

    // A-fragment base offsets (iter stride = 4*256*8 = 8192 ushorts)
    size_t aoff[4];
    #pragma unroll
    for (int m = 0; m < 4; ++m)
        aoff[m] = ((size_t)(l >> 4) * 256 + co_w + 16 * m + (l & 15)) * 8;

    short8v cah[4], cal[4];                          // current A fragments
    #pragma unroll
    for (int m = 0; m < 4; ++m) {
        cah[m] = *(const short8v*)(Wf_hi + aoff[m]);
        cal[m] = *(const short8v*)(Wf_lo + aoff[m]);
    }

    for (int it = 0; it < 18; ++it) {                // it = tap*2 + ks
        const int tap = it >> 1, ks = it & 1;
        const int dy = tap / 3, dx = tap - dy * 3;
        const int toff = dy * 58 + dx;
        const int grp = ks * 4 + (l >> 4);

        short8v nah[4], nal[4];                      // prefetch next iter's A
        {
            const size_t po = (size_t)(it < 17 ? it + 1 : it) * 8192;
            #pragma unroll
            for (int m = 0; m < 4; ++m) {
                nah[m] = *(const short8v*)(Wf_hi + aoff[m] + po);
                nal[m] = *(const short8v*)(Wf_lo + aoff[m] + po);
            }
        }

        #pragma unroll
        for (int nf = 0; nf < 7; ++nf) {
            const int x  = bx[nf] + dx;
            const int bi = ((b58[nf] + toff) << 6) + ((grp ^ (x & 7)) << 3);
            short8v bh  = *(const short8v*)&Bh[bi];
            short8v blv = *(const short8v*)&Bl[bi];
            #pragma unroll
            for (int m = 0; m < 4; ++m) {
                acc[m][nf] = __builtin_amdgcn_mfma_f32_16x16x32_bf16(cah[m], bh,  acc[m][nf], 0, 0, 0);
                acc[m][nf] = __builtin_amdgcn_mfma_f32_16x16x32_bf16(cah[m], blv, acc[m][nf], 0, 0, 0);
                acc[m][nf] = __builtin_amdgcn_mfma_f32_16x16x32_bf16(cal[m], bh,  acc[m][nf], 0, 0, 0);
            }
        }
        #pragma unroll
        for (int m = 0; m < 4; ++m) { cah[m] = nah[m]; cal[m] = nal[m]; }
    }

    // epilogue: D row=(l>>4)*4+r -> co, col=l&15 -> sp (verified m89 layout)
    const int rr = (l >> 4) * 4, cc = l & 15;
    #pragma unroll
    for (int m = 0; m < 4; ++m) {
        const int cb = co_w + 16 * m + rr;
        #pragma unroll
        for (int nf = 0; nf < 7; ++nf) {
            const int p = p0 + nf * 16 + cc;
            #pragma unroll
            for (int r = 0; r < 4; ++r) {
                ushort hi, lo; split_bf(acc[m][nf][r], hi, lo);
                dh[(size_t)(cb + r) * SP + p] = hi;
                dl[(size_t)(cb + r) * SP + p] = lo;
            }
        }
    }
}

// ---------------------------------------------------------------------------
// gemm_a_mfma v4 (unchanged — direct stage, no cross-barrier prefetch)
// ---------------------------------------------------------------------------
__global__ __launch_bounds__(256, 2)
void gemm_a_mfma(const ushort* __restrict__ h1h, const ushort* __restrict__ h1l,
                 const ushort* __restrict__ hnh, const ushort* __restrict__ hnl,
                 float* __restrict__ attn)
{
    __shared__ __align__(16) ushort Ah[64][64];
    __shared__ __align__(16) ushort Al[64][64];
    __shared__ __align__(16) ushort Bh[64][64];
    __shared__ __align__(16) ushort Bl[64][64];
    const int tid = threadIdx.x;
    const int w = tid >> 6, l = tid & 63;
    const int wn = w >> 1, wm = w & 1;              // wave grid 2n x 2m
    const int img = blockIdx.x, tile = blockIdx.y;
    const int n0 = (tile & 3) * 64, m0 = (tile >> 2) * 64;

    const ushort* __restrict__ Ahg = h1h + ((size_t)img * COUT + n0) * SP;
    const ushort* __restrict__ Alg = h1l + ((size_t)img * COUT + n0) * SP;
    const ushort* __restrict__ Bhg = hnh + ((size_t)img * COUT + m0) * SP;
    const ushort* __restrict__ Blg = hnl + ((size_t)img * COUT + m0) * SP;

    f32x4 acc[2][2];
    #pragma unroll
    for (int i = 0; i < 2; ++i)
        #pragma unroll
        for (int j = 0; j < 2; ++j) acc[i][j] = (f32x4){0.f, 0.f, 0.f, 0.f};

    const int ap = tid >> 7, arow = (tid & 127) >> 1, ag0 = (tid & 1) * 4;
    const ushort* __restrict__ Asrc = ap ? Alg : Ahg;
    ushort (* __restrict__ Adst)[64] = ap ? Al : Ah;
    const ushort* __restrict__ Bsrc = ap ? Blg : Bhg;
    ushort (* __restrict__ Bdst)[64] = ap ? Bl : Bh;

    const ushort* aptr = Asrc + (size_t)arow * SP + ag0 * 8;
    const ushort* bptr = Bsrc + (size_t)arow * SP + ag0 * 8;

    for (int k0 = 0; k0 < SP; k0 += 64) {
        #pragma unroll
        for (int j = 0; j < 4; ++j) {
            uint4 va = ((const uint4*)(aptr + k0))[j];
            *(uint4*)&Adst[arow][SWZ(arow, ag0 + j)] = va;
            uint4 vb = ((const uint4*)(bptr + k0))[j];
            *(uint4*)&Bdst[arow][SWZ(arow, ag0 + j)] = vb;
        }
        __syncthreads();

        #pragma unroll
        for (int ks = 0; ks < 2; ++ks) {
            const int grp = ks * 4 + (l >> 4);
            short8v ahf[2], alf[2], bhf[2], blf[2];
            #pragma unroll
            for (int i = 0; i < 2; ++i) {
                const int ar_ = 32 * wn + 16 * i + (l & 15);
                ahf[i] = *(const short8v*)&Ah[ar_][SWZ(ar_, grp)];
                alf[i] = *(const short8v*)&Al[ar_][SWZ(ar_, grp)];
                const int br_ = 32 * wm + 16 * i + (l & 15);
                bhf[i] = *(const short8v*)&Bh[br_][SWZ(br_, grp)];
                blf[i] = *(const short8v*)&Bl[br_][SWZ(br_, grp)];
            }
            #pragma unroll
            for (int i = 0; i < 2; ++i)
                #pragma unroll
                for (int j = 0; j < 2; ++j) {
                    acc[i][j] = __builtin_amdgcn_mfma_f32_16x16x32_bf16(ahf[i], bhf[j], acc[i][j], 0, 0, 0);
                    acc[i][j] = __builtin_amdgcn_mfma_f32_16x16x32_bf16(ahf[i], blf[j], acc[i][j], 0, 0, 0);
                    acc[i][j] = __builtin_amdgcn_mfma_f32_16x16x32_bf16(alf[i], bhf[j], acc[i][j], 0, 0, 0);
                }
        }
        __syncthreads();
    }

    const int rr = (l >> 4) * 4, cc = l & 15;
    float* __restrict__ aimg = attn + (size_t)img * COUT * COUT;
    #pragma unroll
    for (int i = 0; i < 2; ++i) {
        const int nb = n0 + 32 * wn + 16 * i + rr;
        #pragma unroll
        for (int j = 0; j < 2; ++j) {
            const int m = m0 + 32 * wm + 16 * j + cc;
            #pragma unroll
            for (int r = 0; r < 4; ++r) {
                float v = acc[i][j][r];
                v = (v >= 0.f) ? v : NEG_SLOPE * v;
                aimg[(size_t)(nb + r) * COUT + m] = v;
            }
        }
    }
}

// ---------------------------------------------------------------------------
// softmax over axis n (dim=1) per (b,m) column, in place. (unchanged)
// ---------------------------------------------------------------------------
__global__ __launch_bounds__(64)
void softmax_k(float* __restrict__ attn)
{
    const int b = blockIdx.y;
    const int m = blockIdx.x * 64 + threadIdx.x;
    float* a = attn + (size_t)b * COUT * COUT;
    float mx = -1e30f;
    for (int n_ = 0; n_ < COUT; ++n_) mx = fmaxf(mx, a[n_ * COUT + m]);
    float s = 0.f;
    for (int n_ = 0; n_ < COUT; ++n_) s += expf(a[n_ * COUT + m] - mx);
    float inv = 1.f / s;
    for (int n_ = 0; n_ < COUT; ++n_)
        a[n_ * COUT + m] = expf(a[n_ * COUT + m] - mx) * inv;
}

// ---------------------------------------------------------------------------
// gemm_agg_mfma: out[n][f] = 0.1 * sum_m attn[n][m]*h1[m][f] + 0.9 * h1[n][f]
// (unchanged — 68 VGPR, no spill)
// ---------------------------------------------------------------------------
__global__ __launch_bounds__(256, 2)
void gemm_agg_mfma(const float* __restrict__ attn,
                   const ushort* __restrict__ h1h, const ushort* __restrict__ h1l,
                   float* __restrict__ out)
{
    __shared__ __align__(16) ushort Ah[128][72];
    __shared__ __align__(16) ushort Al[128][72];
    __shared__ __align__(16) ushort Bh[112][72];
    __shared__ __align__(16) ushort Bl[112][72];
    const int tid = threadIdx.x, w = tid >> 6, l = tid & 63;
    const int f0 = blockIdx.x * 112;
    const int n0 = blockIdx.y * 128;
    const int img = blockIdx.z;

    const float*  __restrict__ A  = attn + (size_t)img * COUT * COUT;
    const ushort* __restrict__ Hh = h1h + (size_t)img * COUT * SP;
    const ushort* __restrict__ Hl = h1l + (size_t)img * COUT * SP;

    f32x4 acc[2][7];
    #pragma unroll
    for (int nf = 0; nf < 2; ++nf)
        #pragma unroll
        for (int mf = 0; mf < 7; ++mf) acc[nf][mf] = (f32x4){0.f, 0.f, 0.f, 0.f};

    const int ar = tid >> 1, ac = (tid & 1) * 32;
    const int bp = tid >> 7, bm = (tid & 127) >> 1, bf = (tid & 1) * 56;
    const ushort* __restrict__ Bsrc = bp ? Hl : Hh;
    ushort (* __restrict__ Bdst)[72] = bp ? Bl : Bh;

    for (int k0 = 0; k0 < COUT; k0 += 64) {
        {
            const float* g = A + (size_t)(n0 + ar) * COUT + k0 + ac;
            uint* dh = (uint*)&Ah[ar][ac];
            uint* dl = (uint*)&Al[ar][ac];
            #pragma unroll
            for (int q = 0; q < 8; ++q) {
                float4 v = *(const float4*)(g + 4 * q);
                ushort h0, l0, h1_, l1_, h2, l2, h3, l3;
                split_bf(v.x, h0, l0); split_bf(v.y, h1_, l1_);
                split_bf(v.z, h2, l2); split_bf(v.w, h3, l3);
                dh[2 * q]     = (uint)h0 | ((uint)h1_ << 16);
                dh[2 * q + 1] = (uint)h2 | ((uint)h3  << 16);
                dl[2 * q]     = (uint)l0 | ((uint)l1_ << 16);
                dl[2 * q + 1] = (uint)l2 | ((uint)l3  << 16);
            }
        }
        {
            const ushort* g = Bsrc + (size_t)(k0 + bm) * SP + f0 + bf;
            #pragma unroll
            for (int q = 0; q < 7; ++q) {
                uint4 v = *(const uint4*)(g + 8 * q);
                const ushort* vp = (const ushort*)&v;
                #pragma unroll
                for (int e = 0; e < 8; ++e)
                    Bdst[bf + 8 * q + e][bm] = vp[e];
            }
        }
        __syncthreads();
        #pragma unroll
        for (int ks = 0; ks < 2; ++ks) {
            const int kb = ks * 32 + (l >> 4) * 8;
            short8v ah[2], alv[2];
            #pragma unroll
            for (int nf = 0; nf < 2; ++nf) {
                const int row = 32 * w + 16 * nf + (l & 15);
                ah[nf]  = *(const short8v*)&Ah[row][kb];
                alv[nf] = *(const short8v*)&Al[row][kb];
            }
            #pragma unroll
            for (int mf = 0; mf < 7; ++mf) {
                const int br = mf * 16 + (l & 15);
                short8v bh  = *(const short8v*)&Bh[br][kb];
                short8v blv = *(const short8v*)&Bl[br][kb];
                #pragma unroll
                for (int nf = 0; nf < 2; ++nf) {
                    acc[nf][mf] = __builtin_amdgcn_mfma_f32_16x16x32_bf16(ah[nf],  bh,  acc[nf][mf], 0, 0, 0);
                    acc[nf][mf] = __builtin_amdgcn_mfma_f32_16x16x32_bf16(ah[nf],  blv, acc[nf][mf], 0, 0, 0);
                    acc[nf][mf] = __builtin_amdgcn_mfma_f32_16x16x32_bf16(alv[nf], bh,  acc[nf][mf], 0, 0, 0);
                }
            }
        }
        __syncthreads();
    }

    const int rr = (l >> 4) * 4, cc = l & 15;
    float* __restrict__ orow = out + (size_t)img * COUT * SP;
    #pragma unroll
    for (int nf = 0; nf < 2; ++nf) {
        const int nb = n0 + 32 * w + 16 * nf + rr;
        #pragma unroll
        for (int mf = 0; mf < 7; ++mf) {
            const int f = f0 + 16 * mf + cc;
            #pragma unroll
            for (int r = 0; r < 4; ++r) {
                const int n = nb + r;
                float h = bfr(Hh[(size_t)n * SP + f]) + bfr(Hl[(size_t)n * SP + f]);
                orow[(size_t)n * SP + f] = 0.1f * acc[nf][mf][r] + 0.9f * h;
            }
        }
    }
}

// ---------------------------------------------------------------------------
extern "C" void kernel_launch(void* const* d_in, const int* in_sizes, int n_in,
                              void* d_out, int out_size, void* d_ws, size_t ws_size,
                              hipStream_t stream)
{
    const float* x    = (const float*)d_in[0];
    const float* nn   = (const float*)d_in[1];
    const float* W    = (const float*)d_in[2];
    const float* bias = (const float*)d_in[3];
    float* out = (float*)d_out;

    // ws (111.2 MB): h1b_hi (51.4) | h1b_lo (51.4) | zone (8.39):
    //   conv phase: Wf hi/lo (1.2 MB); gemm phase: attn f32 (overlaps dead Wf).
    ushort* h1b_hi = (ushort*)d_ws;
    ushort* h1b_lo = h1b_hi + (size_t)NB * COUT * SP;
    char*   zone   = (char*)(h1b_lo + (size_t)NB * COUT * SP);
    ushort* Wf_hi  = (ushort*)zone;
    ushort* Wf_lo  = Wf_hi + 9 * 256 * 64;
    float*  attn   = (float*)zone;          // overwrites Wf after convs complete
    // d_out (102.8 MB): hnb_hi | hnb_lo until gemm_agg_mfma overwrites with out f32.
    ushort* hnb_hi = (ushort*)d_out;
    ushort* hnb_lo = hnb_hi + (size_t)NB * COUT * SP;

    pack_w    <<<576, 256, 0, stream>>>(W, Wf_hi, Wf_lo);
    conv_fused<<<dim3(28, 2 * NB), 256, 0, stream>>>(x, nn, Wf_hi, Wf_lo, bias,
                                                     h1b_hi, h1b_lo, hnb_hi, hnb_lo);
    gemm_a_mfma  <<<dim3(32, 16),    256, 0, stream>>>(h1b_hi, h1b_lo, hnb_hi, hnb_lo, attn);
    softmax_k    <<<dim3(4, NB),     64,  0, stream>>>(attn);
    gemm_agg_mfma<<<dim3(28, 2, NB), 256, 0, stream>>>(attn, h1b_hi, h1b_lo, out);
}